// Round 1
// baseline (388.030 us; speedup 1.0000x reference)
//
#include <hip/hip_runtime.h>
#include <hip/hip_fp16.h>

// Fused 8-step diffusion, v2: latency-oriented restructure.
//
// Diagnosis from v1 counters (110us/dispatch, VALUBusy 19%, HBM 12.6%,
// occupancy ~22%): latency-bound, not BW/VALU-bound. VGPR=120 caps residency
// at 16 waves/CU; grid=512 = exactly 2 blocks/CU launched in lockstep, so the
// memory-heavy weight-load phase and the VALU/LDS-heavy 8-step phase never
// overlap across blocks.
//
// v2 layout: 1024 blocks = 4 per (n,c) plane, 512 threads each. Each block
// covers a 48-row window: 32 owned rows + 8-row redundant halo each side
// (wrongness from the window edge propagates 1 row/step; after 8 steps it
// reaches only the first unowned row). 4 block generations per CU pipeline
// load-phase against step-phase. Per thread: 3 rows x 4 cols.
// ALL weights in registers (3 rows x 9 taps fp16 = 54 VGPRs) -> no LDS
// weight path. Boundary-row exchange double-buffered -> ONE barrier/step.
// LDS 32 KB, target VGPR <= 128 (16 waves/CU), no spill.

constexpr int H = 128, W = 128, PLANE = H * W;
constexpr int NSTEP = 8;
constexpr int RPT  = 3;            // rows per thread (48-row window / 16 rg)
constexpr int NRG  = 16;
constexpr int HALO = 8;
constexpr int OWN  = 32;           // owned rows per block (4 blocks/plane)

// 6-wide column window (cols j0-1 .. j0+4) from a float4 row segment
#define MKWIN(D, V) do {                                                     \
    (D)[1] = (V).x; (D)[2] = (V).y; (D)[3] = (V).z; (D)[4] = (V).w;          \
    float _l = __shfl_up((V).w, 1);                                          \
    float _r = __shfl_down((V).x, 1);                                        \
    (D)[0] = (quad == 0)  ? 0.f : _l;                                        \
    (D)[5] = (quad == 31) ? 0.f : _r;                                        \
} while (0)

__global__ __launch_bounds__(512, 4)
void diff_fused(const float* __restrict__ xin,
                const float* __restrict__ wgt,
                float* __restrict__ out)
{
    // double-buffered boundary rows: [buf][rg] top / bottom (32 KB total)
    __shared__ float ldsT[2][NRG][W];
    __shared__ float ldsB[2][NRG][W];

    const int tid   = threadIdx.x;
    const int quad  = tid & 31;         // cols 4q..4q+3
    const int rg    = tid >> 5;         // 0..15
    const int j0    = quad * 4;
    const int plane = blockIdx.x >> 2;
    const int qtr   = blockIdx.x & 3;
    const int rbase = qtr * OWN - HALO;         // window start row
    const int r0    = rbase + rg * RPT;         // this thread's first row
    const size_t pbase = (size_t)plane * PLANE;

    const float* __restrict__ xp = xin + pbase;
    const float* __restrict__ wb = wgt + pbase * 9;

    // ---- weights: load once, |.|-normalize fp32, pack fp16, ALL in regs ----
    __half2 wh[RPT][9][2];              // 54 VGPRs
    #pragma unroll
    for (int p = 0; p < RPT; ++p) {
        const int  gr  = r0 + p;
        const bool inr = (unsigned)gr < (unsigned)H;
        const float* wr = wb + gr * W + j0;
        float a[9][4];
        float s0 = 0.f, s1 = 0.f, s2 = 0.f, s3 = 0.f;
        #pragma unroll
        for (int k = 0; k < 9; ++k) {
            float4 v = make_float4(1.f, 1.f, 1.f, 1.f);  // dummy for pad rows
            if (inr) v = *reinterpret_cast<const float4*>(wr + (size_t)k * PLANE);
            a[k][0] = fabsf(v.x); a[k][1] = fabsf(v.y);
            a[k][2] = fabsf(v.z); a[k][3] = fabsf(v.w);
            s0 += a[k][0]; s1 += a[k][1]; s2 += a[k][2]; s3 += a[k][3];
        }
        s0 = 1.f / s0; s1 = 1.f / s1; s2 = 1.f / s2; s3 = 1.f / s3;
        #pragma unroll
        for (int k = 0; k < 9; ++k) {
            wh[p][k][0] = __halves2half2(__float2half_rn(a[k][0] * s0),
                                         __float2half_rn(a[k][1] * s1));
            wh[p][k][1] = __halves2half2(__float2half_rn(a[k][2] * s2),
                                         __float2half_rn(a[k][3] * s3));
        }
    }

    // ---- x window into registers (pad rows -> 0) ----
    float4 xr[RPT];
    #pragma unroll
    for (int p = 0; p < RPT; ++p) {
        const int gr = r0 + p;
        xr[p] = make_float4(0.f, 0.f, 0.f, 0.f);
        if ((unsigned)gr < (unsigned)H)
            xr[p] = *reinterpret_cast<const float4*>(xp + gr * W + j0);
    }

    // prologue: publish step-0 boundary rows into buffer 0
    *reinterpret_cast<float4*>(&ldsT[0][rg][j0]) = xr[0];
    *reinterpret_cast<float4*>(&ldsB[0][rg][j0]) = xr[RPT - 1];
    __syncthreads();

    // ---- 8 fused steps, zero global traffic, ONE barrier per step ----
    #pragma unroll 1
    for (int s = 0; s < NSTEP; ++s) {
        const int cur = s & 1;
        float4 up = make_float4(0.f, 0.f, 0.f, 0.f);   // row r0-1
        float4 dn = make_float4(0.f, 0.f, 0.f, 0.f);   // row r0+3
        if (rg > 0)       up = *reinterpret_cast<const float4*>(&ldsB[cur][rg - 1][j0]);
        if (rg < NRG - 1) dn = *reinterpret_cast<const float4*>(&ldsT[cur][rg + 1][j0]);

        float win[3][6];
        MKWIN(win[0], up);       // input row r0-1
        MKWIN(win[1], xr[0]);    // input row r0
        #pragma unroll
        for (int p = 0; p < RPT; ++p) {
            if (p < RPT - 1) { MKWIN(win[(p + 2) % 3], xr[p + 1]); }
            else             { MKWIN(win[(p + 2) % 3], dn); }
            float a0 = 0.f, a1 = 0.f, a2 = 0.f, a3 = 0.f;
            #pragma unroll
            for (int di = 0; di < 3; ++di) {
                #pragma unroll
                for (int dj = 0; dj < 3; ++dj) {
                    const int k = di * 3 + dj;
                    const __half2 w0 = wh[p][k][0];
                    const __half2 w1 = wh[p][k][1];
                    a0 = fmaf(__low2float (w0), win[(p + di) % 3][dj + 0], a0);
                    a1 = fmaf(__high2float(w0), win[(p + di) % 3][dj + 1], a1);
                    a2 = fmaf(__low2float (w1), win[(p + di) % 3][dj + 2], a2);
                    a3 = fmaf(__high2float(w1), win[(p + di) % 3][dj + 3], a3);
                }
            }
            xr[p] = make_float4(a0, a1, a2, a3);
        }
        // re-impose zero padding (keeps pad rows 0 every step)
        #pragma unroll
        for (int p = 0; p < RPT; ++p) {
            const int gr = r0 + p;
            if ((unsigned)gr >= (unsigned)H)
                xr[p] = make_float4(0.f, 0.f, 0.f, 0.f);
        }
        // publish next step's boundary rows into the other buffer.
        // Single barrier separates this step's reads of buf[cur] from the
        // next step's writes to buf[cur]. Last step: skip (nothing reads it).
        if (s < NSTEP - 1) {
            *reinterpret_cast<float4*>(&ldsT[cur ^ 1][rg][j0]) = xr[0];
            *reinterpret_cast<float4*>(&ldsB[cur ^ 1][rg][j0]) = xr[RPT - 1];
            __syncthreads();
        }
    }

    // ---- store owned rows only (coalesced float4) ----
    float* __restrict__ op = out + pbase;
    #pragma unroll
    for (int p = 0; p < RPT; ++p) {
        const int gr = r0 + p;
        const int lr = gr - rbase - HALO;
        if ((unsigned)lr < (unsigned)OWN)
            *reinterpret_cast<float4*>(op + gr * W + j0) = xr[p];
    }
}

extern "C" void kernel_launch(void* const* d_in, const int* in_sizes, int n_in,
                              void* d_out, int out_size, void* d_ws, size_t ws_size,
                              hipStream_t stream)
{
    const float* x = (const float*)d_in[0];
    const float* w = (const float*)d_in[1];
    float* out = (float*)d_out;
    (void)d_ws; (void)ws_size; (void)in_sizes; (void)n_in; (void)out_size;

    // 1024 blocks = 4 per plane (4n x 64c), 512 threads
    diff_fused<<<dim3(4 * 4 * 64), dim3(512), 0, stream>>>(x, w, out);
}

// Round 3
// 287.094 us; speedup vs baseline: 1.3516x; 1.3516x over previous
//
#include <hip/hip_runtime.h>
#include <hip/hip_fp16.h>

// Fused 8-step diffusion, v4: v3 layout + v1-proven two-barrier exchange.
//
// v3 post-mortem: passed pre-timing correctness but diverged (absmax 0.38)
// after graph-replay timing -> scheduling-dependent race. Only plausible
// site: the single-barrier double-buffered boundary exchange (source-level
// region analysis says race-free, but codegen evidently reorders an LDS read
// across the barrier under the un-spilled register schedule). v2 "passed"
// the same structure only under spill-dominated timing.
//
// v4 reverts the exchange to v1's battle-tested pattern:
//     write boundary rows -> __syncthreads -> read up/dn -> __syncthreads
// (2 barriers/step, single 16KB buffer). Everything else keeps the v3
// restructure, now finally measured without spill:
//   - 1024 blocks = 4 per (n,c) plane, 512 threads. 48-row window =
//     32 owned + 8-row redundant halo each side (edge wrongness moves
//     1 row/step; 8 steps never reach an owned row). 3 rows x 4 cols/thread.
//   - ALL weights in registers (3 rows x 9 taps fp16 = 54 VGPRs), no LDS
//     weight path.
//   - plain __launch_bounds__(512): v2's (512,4) forced a 64-VGPR cap ->
//     121 MB scratch-spill writes. Target ~100-124 VGPR, 2 blocks/CU ->
//     2 block generations pipelining load-phase against step-phase.

constexpr int H = 128, W = 128, PLANE = H * W;
constexpr int NSTEP = 8;
constexpr int RPT  = 3;            // rows per thread (48-row window / 16 rg)
constexpr int NRG  = 16;
constexpr int HALO = 8;
constexpr int OWN  = 32;           // owned rows per block (4 blocks/plane)

// 6-wide column window (cols j0-1 .. j0+4) from a float4 row segment
#define MKWIN(D, V) do {                                                     \
    (D)[1] = (V).x; (D)[2] = (V).y; (D)[3] = (V).z; (D)[4] = (V).w;          \
    float _l = __shfl_up((V).w, 1);                                          \
    float _r = __shfl_down((V).x, 1);                                        \
    (D)[0] = (quad == 0)  ? 0.f : _l;                                        \
    (D)[5] = (quad == 31) ? 0.f : _r;                                        \
} while (0)

__global__ __launch_bounds__(512)
void diff_fused(const float* __restrict__ xin,
                const float* __restrict__ wgt,
                float* __restrict__ out)
{
    __shared__ float ldsT[NRG][W];      // each rg's top row    (8 KB)
    __shared__ float ldsB[NRG][W];      // each rg's bottom row (8 KB)

    const int tid   = threadIdx.x;
    const int quad  = tid & 31;         // cols 4q..4q+3
    const int rg    = tid >> 5;         // 0..15
    const int j0    = quad * 4;
    const int plane = blockIdx.x >> 2;
    const int qtr   = blockIdx.x & 3;
    const int rbase = qtr * OWN - HALO;         // window start row
    const int r0    = rbase + rg * RPT;         // this thread's first row
    const size_t pbase = (size_t)plane * PLANE;

    const float* __restrict__ xp = xin + pbase;
    const float* __restrict__ wb = wgt + pbase * 9;

    // ---- weights: load once, |.|-normalize fp32, pack fp16, ALL in regs ----
    __half2 wh[RPT][9][2];              // 54 VGPRs
    #pragma unroll
    for (int p = 0; p < RPT; ++p) {
        const int  gr  = r0 + p;
        const bool inr = (unsigned)gr < (unsigned)H;
        const float* wr = wb + gr * W + j0;
        float a[9][4];
        float s0 = 0.f, s1 = 0.f, s2 = 0.f, s3 = 0.f;
        #pragma unroll
        for (int k = 0; k < 9; ++k) {
            float4 v = make_float4(1.f, 1.f, 1.f, 1.f);  // dummy for pad rows
            if (inr) v = *reinterpret_cast<const float4*>(wr + (size_t)k * PLANE);
            a[k][0] = fabsf(v.x); a[k][1] = fabsf(v.y);
            a[k][2] = fabsf(v.z); a[k][3] = fabsf(v.w);
            s0 += a[k][0]; s1 += a[k][1]; s2 += a[k][2]; s3 += a[k][3];
        }
        s0 = 1.f / s0; s1 = 1.f / s1; s2 = 1.f / s2; s3 = 1.f / s3;
        #pragma unroll
        for (int k = 0; k < 9; ++k) {
            wh[p][k][0] = __halves2half2(__float2half_rn(a[k][0] * s0),
                                         __float2half_rn(a[k][1] * s1));
            wh[p][k][1] = __halves2half2(__float2half_rn(a[k][2] * s2),
                                         __float2half_rn(a[k][3] * s3));
        }
    }

    // ---- x window into registers (pad rows -> 0) ----
    float4 xr[RPT];
    #pragma unroll
    for (int p = 0; p < RPT; ++p) {
        const int gr = r0 + p;
        xr[p] = make_float4(0.f, 0.f, 0.f, 0.f);
        if ((unsigned)gr < (unsigned)H)
            xr[p] = *reinterpret_cast<const float4*>(xp + gr * W + j0);
    }

    // ---- 8 fused steps, zero global traffic, two barriers/step (v1-proven) ----
    #pragma unroll 1
    for (int s = 0; s < NSTEP; ++s) {
        *reinterpret_cast<float4*>(&ldsT[rg][j0]) = xr[0];
        *reinterpret_cast<float4*>(&ldsB[rg][j0]) = xr[RPT - 1];
        __syncthreads();
        float4 up = make_float4(0.f, 0.f, 0.f, 0.f);   // row r0-1
        float4 dn = make_float4(0.f, 0.f, 0.f, 0.f);   // row r0+3
        if (rg > 0)       up = *reinterpret_cast<const float4*>(&ldsB[rg - 1][j0]);
        if (rg < NRG - 1) dn = *reinterpret_cast<const float4*>(&ldsT[rg + 1][j0]);
        __syncthreads();   // reads done before next step's writes

        float win[3][6];
        MKWIN(win[0], up);       // input row r0-1
        MKWIN(win[1], xr[0]);    // input row r0
        #pragma unroll
        for (int p = 0; p < RPT; ++p) {
            if (p < RPT - 1) { MKWIN(win[(p + 2) % 3], xr[p + 1]); }
            else             { MKWIN(win[(p + 2) % 3], dn); }
            float a0 = 0.f, a1 = 0.f, a2 = 0.f, a3 = 0.f;
            #pragma unroll
            for (int di = 0; di < 3; ++di) {
                #pragma unroll
                for (int dj = 0; dj < 3; ++dj) {
                    const int k = di * 3 + dj;
                    const __half2 w0 = wh[p][k][0];
                    const __half2 w1 = wh[p][k][1];
                    a0 = fmaf(__low2float (w0), win[(p + di) % 3][dj + 0], a0);
                    a1 = fmaf(__high2float(w0), win[(p + di) % 3][dj + 1], a1);
                    a2 = fmaf(__low2float (w1), win[(p + di) % 3][dj + 2], a2);
                    a3 = fmaf(__high2float(w1), win[(p + di) % 3][dj + 3], a3);
                }
            }
            xr[p] = make_float4(a0, a1, a2, a3);
        }
        // re-impose zero padding (keeps pad rows 0 every step)
        #pragma unroll
        for (int p = 0; p < RPT; ++p) {
            const int gr = r0 + p;
            if ((unsigned)gr >= (unsigned)H)
                xr[p] = make_float4(0.f, 0.f, 0.f, 0.f);
        }
    }

    // ---- store owned rows only (coalesced float4) ----
    float* __restrict__ op = out + pbase;
    #pragma unroll
    for (int p = 0; p < RPT; ++p) {
        const int gr = r0 + p;
        const int lr = gr - rbase - HALO;
        if ((unsigned)lr < (unsigned)OWN)
            *reinterpret_cast<float4*>(op + gr * W + j0) = xr[p];
    }
}

extern "C" void kernel_launch(void* const* d_in, const int* in_sizes, int n_in,
                              void* d_out, int out_size, void* d_ws, size_t ws_size,
                              hipStream_t stream)
{
    const float* x = (const float*)d_in[0];
    const float* w = (const float*)d_in[1];
    float* out = (float*)d_out;
    (void)d_ws; (void)ws_size; (void)in_sizes; (void)n_in; (void)out_size;

    // 1024 blocks = 4 per plane (4n x 64c), 512 threads
    diff_fused<<<dim3(4 * 4 * 64), dim3(512), 0, stream>>>(x, w, out);
}